// Round 1
// baseline (715.649 us; speedup 1.0000x reference)
//
#include <hip/hip_runtime.h>

// Infusion: local dilated-window attention, float32 end-to-end.
// N=8, C=256 (8 heads x 32 ch), H=W=128, ksize=5, dilation=3, pad=6, 25 taps.
//
// V2: cooperative LDS staging. Per channel, the block stages the 20-row
// (rows Rb-6 .. Rb+13) x 128-col K/V window into a zero-padded LDS tile
// [20][144] (col = x + 8). Borders (cols 0..7, 136..143) and out-of-bounds
// rows are zeroed once at kernel start and never overwritten, so padding
// semantics (padded taps score exactly 0, padded V adds 0) fall out with
// ZERO masking instructions in the inner loop.
//
// Software pipeline (T14): global loads for channel c+1 are issued into
// registers before the compute of channel c (reg loads stay in flight
// across __syncthreads); the reg->LDS write lands after the barrier.
//
// Thread mapping unchanged: thread = 4 consecutive x pixels; block = 32x8
// threads = 128x8 tile; blockIdx.y = n*8+head. Scores s[4][25] in VGPRs.

#define Hh 128
#define Ww 128
#define HD 32
#define TAPS 25
#define LROWS 20
#define LSTR 144   // LDS row stride in floats; col = x + 8; interior cols 8..135

__global__ __launch_bounds__(256, 2) void infusion_kernel(
    const float* __restrict__ Vt,
    const float* __restrict__ Kt,
    const float* __restrict__ Qt,
    float* __restrict__ Ot)
{
    __shared__ float lk[LROWS][LSTR];

    const int tid = threadIdx.x;
    const int tx  = tid & 31;   // x-group (4 pixels each)
    const int ty  = tid >> 5;   // 0..7
    const int Rb  = blockIdx.x * 8;
    const int row = Rb + ty;
    const int nh  = blockIdx.y; // n*8 + head
    const int xs  = tx << 2;

    const size_t plane = (size_t)Hh * Ww;
    const size_t cbase = (size_t)nh * HD * plane;
    const int qoff = row * Ww + xs;

    // ---- zero the whole tile once; borders and OOB rows stay zero forever ----
    for (int i = tid; i < LROWS * LSTR; i += 256)
        (&lk[0][0])[i] = 0.f;

    // ---- staging map: 640 chunks of 16B (20 rows x 32 xchunks) ----
    // thread t handles chunks t, t+256, t+512 (t<128). Consecutive t ->
    // consecutive 16B in global (coalesced) and in LDS (conflict-free).
    bool   sgv[3];
    int    sgo[3];
    float* sgl[3];
#pragma unroll
    for (int k = 0; k < 3; ++k) {
        const int q  = tid + (k << 8);
        const int lr = q >> 5, xc = q & 31;
        const int r  = Rb + lr - 6;
        const bool ok = (q < 640) && (r >= 0) && (r < Hh);
        sgv[k] = ok;
        sgo[k] = ok ? (r * Ww + (xc << 2)) : 0;
        sgl[k] = &lk[(lr < LROWS) ? lr : 0][8 + (xc << 2)];
    }

    float s[4][TAPS];
#pragma unroll
    for (int a = 0; a < 4; ++a)
#pragma unroll
        for (int p = 0; p < TAPS; ++p) s[a][p] = 0.f;

    // ---------------- phase 1: scores = K . Q over 32 channels ----------------
    {
        const float* Kb = Kt + cbase;
        const float* Qb = Qt + cbase;
        float4 st[3];
#pragma unroll
        for (int k = 0; k < 3; ++k)
            if (sgv[k]) st[k] = *(const float4*)(Kb + sgo[k]);
        __syncthreads();  // zero-init visible to all
        for (int c = 0; c < HD; ++c) {
            // commit staged channel c to LDS (compiler inserts vmcnt wait)
#pragma unroll
            for (int k = 0; k < 3; ++k)
                if (sgv[k]) *(float4*)sgl[k] = st[k];
            __syncthreads();
            // prefetch channel c+1 into registers (in flight across compute)
            if (c + 1 < HD) {
                const float* Kn = Kb + (size_t)(c + 1) * plane;
#pragma unroll
                for (int k = 0; k < 3; ++k)
                    if (sgv[k]) st[k] = *(const float4*)(Kn + sgo[k]);
            }
            const float4 qv = *(const float4*)(Qb + (size_t)c * plane + qoff);
#pragma unroll
            for (int fy = 0; fy < 5; ++fy) {
                // 16 floats at x = xs-6 .. xs+9  ->  cols xs+2 .. xs+17
                // byte offset = 16*tx + 8 (mod 16): 8B-aligned float2 reads,
                // stride-16B across lanes -> bank-conflict-free.
                const float2* vr = (const float2*)(&lk[ty + 3 * fy][xs + 2]);
                const float2 w0 = vr[0], w1 = vr[1], w2 = vr[2], w3 = vr[3];
                const float2 w4 = vr[4], w5 = vr[5], w6 = vr[6], w7 = vr[7];
                const float v[16] = { w0.x, w0.y, w1.x, w1.y,
                                      w2.x, w2.y, w3.x, w3.y,
                                      w4.x, w4.y, w5.x, w5.y,
                                      w6.x, w6.y, w7.x, w7.y };
#pragma unroll
                for (int fx = 0; fx < 5; ++fx) {
                    const int p = fy * 5 + fx;
                    s[0][p] = fmaf(v[0 + 3 * fx], qv.x, s[0][p]);
                    s[1][p] = fmaf(v[1 + 3 * fx], qv.y, s[1][p]);
                    s[2][p] = fmaf(v[2 + 3 * fx], qv.z, s[2][p]);
                    s[3][p] = fmaf(v[3 + 3 * fx], qv.w, s[3][p]);
                }
            }
            __syncthreads();  // all waves done reading before next ds_write
        }
    }

    // ---------------- preload V channel 0 (hide under softmax) ----------------
    const float* Vb = Vt + cbase;
    float*       Ob = Ot + cbase;
    float4 stv[3];
#pragma unroll
    for (int k = 0; k < 3; ++k)
        if (sgv[k]) stv[k] = *(const float4*)(Vb + sgo[k]);

    // ---------------- softmax over the 25 taps ----------------
#pragma unroll
    for (int a = 0; a < 4; ++a) {
        float m = s[a][0];
#pragma unroll
        for (int p = 1; p < TAPS; ++p) m = fmaxf(m, s[a][p]);
        float sum = 0.f;
#pragma unroll
        for (int p = 0; p < TAPS; ++p) { float e = __expf(s[a][p] - m); s[a][p] = e; sum += e; }
        const float rs = 1.0f / sum;
#pragma unroll
        for (int p = 0; p < TAPS; ++p) s[a][p] *= rs;
    }

    // ---------------- phase 2: out = sum_p att[p] * V_shift[p] ----------------
    {
        for (int c = 0; c < HD; ++c) {
#pragma unroll
            for (int k = 0; k < 3; ++k)
                if (sgv[k]) *(float4*)sgl[k] = stv[k];
            __syncthreads();
            if (c + 1 < HD) {
                const float* Vn = Vb + (size_t)(c + 1) * plane;
#pragma unroll
                for (int k = 0; k < 3; ++k)
                    if (sgv[k]) stv[k] = *(const float4*)(Vn + sgo[k]);
            }
            float a0 = 0.f, a1 = 0.f, a2 = 0.f, a3 = 0.f;
#pragma unroll
            for (int fy = 0; fy < 5; ++fy) {
                const float2* vr = (const float2*)(&lk[ty + 3 * fy][xs + 2]);
                const float2 w0 = vr[0], w1 = vr[1], w2 = vr[2], w3 = vr[3];
                const float2 w4 = vr[4], w5 = vr[5], w6 = vr[6], w7 = vr[7];
                const float v[16] = { w0.x, w0.y, w1.x, w1.y,
                                      w2.x, w2.y, w3.x, w3.y,
                                      w4.x, w4.y, w5.x, w5.y,
                                      w6.x, w6.y, w7.x, w7.y };
#pragma unroll
                for (int fx = 0; fx < 5; ++fx) {
                    const int p = fy * 5 + fx;
                    a0 = fmaf(v[0 + 3 * fx], s[0][p], a0);
                    a1 = fmaf(v[1 + 3 * fx], s[1][p], a1);
                    a2 = fmaf(v[2 + 3 * fx], s[2][p], a2);
                    a3 = fmaf(v[3 + 3 * fx], s[3][p], a3);
                }
            }
            *(float4*)(Ob + (size_t)c * plane + qoff) = make_float4(a0, a1, a2, a3);
            __syncthreads();  // all waves done reading before next ds_write
        }
    }
}

extern "C" void kernel_launch(void* const* d_in, const int* in_sizes, int n_in,
                              void* d_out, int out_size, void* d_ws, size_t ws_size,
                              hipStream_t stream) {
    const float* V = (const float*)d_in[0];
    const float* K = (const float*)d_in[1];
    const float* Q = (const float*)d_in[2];
    // d_in[3] = ksize (5), d_in[4] = dilation (3): fixed by setup_inputs.
    float* O = (float*)d_out;

    const int N = in_sizes[0] / (256 * Hh * Ww);  // = 8
    dim3 grid(Hh / 8, N * 8);
    dim3 block(256);
    infusion_kernel<<<grid, block, 0, stream>>>(V, K, Q, O);
}

// Round 2
// 442.018 us; speedup vs baseline: 1.6191x; 1.6191x over previous
//
#include <hip/hip_runtime.h>

// Infusion: local dilated-window attention, float32 end-to-end.
// N=8, C=256 (8 heads x 32 ch), H=W=128, ksize=5, dilation=3, pad=6, 25 taps.
//
// V3: double-buffered LDS staging, 2 channels per barrier period.
//  - __syncthreads() on gfx950 drains vmcnt(0) (compiler-enforced), so async
//    depth is capped at one barrier period. We make the period = 2 channels:
//    prefetch for period i+1 is issued at the top of period i and has the
//    full 2-channel compute phase (~1000 cyc) to cover HBM latency before the
//    drain at the period-ending barrier. One barrier per 2 channels.
//  - Q is pipelined one period ahead (qn -> qc), killing the per-channel
//    dependent load->use chain of V2.
//  - LSTR = 142 (= 2 mod 4): lane tx starts at word 4*tx+2 (8 bank-pairs);
//    ty-adjacent rows shift by 142%32=14 = 2 mod 4, landing on the opposite
//    bank class -> all 32 banks hit exactly 4x per ds_read_b64 wave = the
//    wave64 floor (V2's LSTR=144 gave 8x -> 3.9e7 conflict cycles).
//  - Zero-padded tile borders + OOB rows zeroed once, never rewritten:
//    padding semantics with zero masking in the inner loop.
// Row byte-stride = 568 (8B-aligned only) -> LDS writes are explicit float2.

#define Hh 128
#define Ww 128
#define HD 32
#define TAPS 25
#define LROWS 20
#define LSTR 142           // floats; col = x + 8; interior cols 8..135
#define CHW (LROWS * LSTR) // 2840 floats per channel tile
#define BUFW (2 * CHW)     // 5680 floats per 2-channel buffer

__global__ __launch_bounds__(256, 2) void infusion_kernel(
    const float* __restrict__ Vt,
    const float* __restrict__ Kt,
    const float* __restrict__ Qt,
    float* __restrict__ Ot)
{
    __shared__ float lbuf[2][BUFW];  // 45440 B

    const int tid = threadIdx.x;
    const int tx  = tid & 31;   // x-group (4 pixels each)
    const int ty  = tid >> 5;   // 0..7
    const int Rb  = blockIdx.x * 8;
    const int row = Rb + ty;
    const int nh  = blockIdx.y; // n*8 + head
    const int xs  = tx << 2;

    const size_t plane = (size_t)Hh * Ww;
    const size_t cbase = (size_t)nh * HD * plane;
    const int qoff = row * Ww + xs;

    // staging map: 640 chunks of 16B (20 rows x 32 xchunks) per channel.
    // thread t handles chunks t, t+256, t+512 (t<128): coalesced in global,
    // conflict-free in LDS. Invalid chunks load row start (safe) & skip write.
    bool sgv[3]; int sgo[3]; int sgl[3];
#pragma unroll
    for (int k = 0; k < 3; ++k) {
        const int q  = tid + (k << 8);
        const int lr = q >> 5, xc = q & 31;
        const int r  = Rb + lr - 6;
        const bool ok = (q < 640) && (r >= 0) && (r < Hh);
        sgv[k] = ok;
        sgo[k] = ok ? (r * Ww + (xc << 2)) : 0;
        sgl[k] = (lr < LROWS ? lr : 0) * LSTR + 8 + (xc << 2);
    }

    // zero both buffers once; borders and OOB rows stay zero forever
    for (int i = tid; i < 2 * BUFW; i += 256) (&lbuf[0][0])[i] = 0.f;

    float4 stg[6];  // staged group (2 channels x 3 chunks), in flight across compute

    auto loadg = [&](const float* Base, int g) {  // issue group = channels g, g+1
        const float* p0 = Base + (size_t)g * plane;
        const float* p1 = p0 + plane;
        stg[0] = *(const float4*)(p0 + sgo[0]);
        stg[1] = *(const float4*)(p0 + sgo[1]);
        stg[2] = *(const float4*)(p0 + sgo[2]);
        stg[3] = *(const float4*)(p1 + sgo[0]);
        stg[4] = *(const float4*)(p1 + sgo[1]);
        stg[5] = *(const float4*)(p1 + sgo[2]);
    };
    auto writeg = [&](int bi) {
#pragma unroll
        for (int cc = 0; cc < 2; ++cc)
#pragma unroll
            for (int k = 0; k < 3; ++k)
                if (sgv[k]) {
                    float* p = &lbuf[bi][cc * CHW + sgl[k]];
                    const float4 v = stg[cc * 3 + k];
                    *(float2*)(p)     = make_float2(v.x, v.y);
                    *(float2*)(p + 2) = make_float2(v.z, v.w);
                }
    };

    float s[4][TAPS];
#pragma unroll
    for (int a = 0; a < 4; ++a)
#pragma unroll
        for (int p = 0; p < TAPS; ++p) s[a][p] = 0.f;

    // ---------------- phase 1: scores = K . Q over 32 channels ----------------
    {
        const float* Kb = Kt + cbase;
        const float* Qb = Qt + cbase;
        float4 qc0 = *(const float4*)(Qb + qoff);
        float4 qc1 = *(const float4*)(Qb + plane + qoff);
        float4 qn0 = qc0, qn1 = qc1;
        loadg(Kb, 0);
        __syncthreads();          // zero-init visible (drains group-0 loads)
        writeg(0);
        loadg(Kb, 2);
        __syncthreads();          // buf0 visible
#pragma unroll 1
        for (int it = 0; it < 16; ++it) {
            if (it < 15) writeg((it + 1) & 1);           // stg = group it+1 (complete)
            if (it < 14) loadg(Kb, 2 * it + 4);          // issue group it+2
            if (it < 15) {                                // issue Q for group it+1
                qn0 = *(const float4*)(Qb + (size_t)(2 * it + 2) * plane + qoff);
                qn1 = *(const float4*)(Qb + (size_t)(2 * it + 3) * plane + qoff);
            }
            const float* lb = &lbuf[it & 1][0];
#pragma unroll
            for (int cc = 0; cc < 2; ++cc) {
                const float4 q = cc ? qc1 : qc0;
#pragma unroll
                for (int fy = 0; fy < 5; ++fy) {
                    const float2* vr =
                        (const float2*)(lb + cc * CHW + (ty + 3 * fy) * LSTR + xs + 2);
                    const float2 w0 = vr[0], w1 = vr[1], w2 = vr[2], w3 = vr[3];
                    const float2 w4 = vr[4], w5 = vr[5], w6 = vr[6], w7 = vr[7];
                    const float v[16] = { w0.x, w0.y, w1.x, w1.y,
                                          w2.x, w2.y, w3.x, w3.y,
                                          w4.x, w4.y, w5.x, w5.y,
                                          w6.x, w6.y, w7.x, w7.y };
#pragma unroll
                    for (int fx = 0; fx < 5; ++fx) {
                        const int p = fy * 5 + fx;
                        s[0][p] = fmaf(v[0 + 3 * fx], q.x, s[0][p]);
                        s[1][p] = fmaf(v[1 + 3 * fx], q.y, s[1][p]);
                        s[2][p] = fmaf(v[2 + 3 * fx], q.z, s[2][p]);
                        s[3][p] = fmaf(v[3 + 3 * fx], q.w, s[3][p]);
                    }
                }
            }
            __syncthreads();     // drains this period's prefetch (full-period slack)
            if (it < 15) { qc0 = qn0; qc1 = qn1; }
        }
    }

    // ---------------- phase 2 prologue: V group 0 in flight under softmax ----
    const float* Vb = Vt + cbase;
    float*       Ob = Ot + cbase;
    loadg(Vb, 0);

    // ---------------- softmax over the 25 taps ----------------
#pragma unroll
    for (int a = 0; a < 4; ++a) {
        float m = s[a][0];
#pragma unroll
        for (int p = 1; p < TAPS; ++p) m = fmaxf(m, s[a][p]);
        float sum = 0.f;
#pragma unroll
        for (int p = 0; p < TAPS; ++p) { float e = __expf(s[a][p] - m); s[a][p] = e; sum += e; }
        const float rs = 1.0f / sum;
#pragma unroll
        for (int p = 0; p < TAPS; ++p) s[a][p] *= rs;
    }

    // ---------------- phase 2: out = sum_p att[p] * V_shift[p] ----------------
    {
        writeg(0);               // waits on the softmax-covered loads
        loadg(Vb, 2);
        __syncthreads();
#pragma unroll 1
        for (int it = 0; it < 16; ++it) {
            if (it < 15) writeg((it + 1) & 1);
            if (it < 14) loadg(Vb, 2 * it + 4);
            const float* lb = &lbuf[it & 1][0];
#pragma unroll
            for (int cc = 0; cc < 2; ++cc) {
                float a0 = 0.f, a1 = 0.f, a2 = 0.f, a3 = 0.f;
#pragma unroll
                for (int fy = 0; fy < 5; ++fy) {
                    const float2* vr =
                        (const float2*)(lb + cc * CHW + (ty + 3 * fy) * LSTR + xs + 2);
                    const float2 w0 = vr[0], w1 = vr[1], w2 = vr[2], w3 = vr[3];
                    const float2 w4 = vr[4], w5 = vr[5], w6 = vr[6], w7 = vr[7];
                    const float v[16] = { w0.x, w0.y, w1.x, w1.y,
                                          w2.x, w2.y, w3.x, w3.y,
                                          w4.x, w4.y, w5.x, w5.y,
                                          w6.x, w6.y, w7.x, w7.y };
#pragma unroll
                    for (int fx = 0; fx < 5; ++fx) {
                        const int p = fy * 5 + fx;
                        a0 = fmaf(v[0 + 3 * fx], s[0][p], a0);
                        a1 = fmaf(v[1 + 3 * fx], s[1][p], a1);
                        a2 = fmaf(v[2 + 3 * fx], s[2][p], a2);
                        a3 = fmaf(v[3 + 3 * fx], s[3][p], a3);
                    }
                }
                *(float4*)(Ob + (size_t)(2 * it + cc) * plane + qoff) =
                    make_float4(a0, a1, a2, a3);
            }
            __syncthreads();
        }
    }
}

extern "C" void kernel_launch(void* const* d_in, const int* in_sizes, int n_in,
                              void* d_out, int out_size, void* d_ws, size_t ws_size,
                              hipStream_t stream) {
    const float* V = (const float*)d_in[0];
    const float* K = (const float*)d_in[1];
    const float* Q = (const float*)d_in[2];
    // d_in[3] = ksize (5), d_in[4] = dilation (3): fixed by setup_inputs.
    float* O = (float*)d_out;

    const int N = in_sizes[0] / (256 * Hh * Ww);  // = 8
    dim3 grid(Hh / 8, N * 8);
    dim3 block(256);
    infusion_kernel<<<grid, block, 0, stream>>>(V, K, Q, O);
}